// Round 5
// baseline (19.060 us; speedup 1.0000x reference)
//
#include <hip/hip_runtime.h>
#include <math.h>

// ============================================================================
// Single fused kernel, zero barriers / zero LDS.
//
// logit(x0,x1) = u0^T K u1,  u0=[1,cos x0,sin x0], u1=[1,cos x1,sin x1],
// K folded with W[0] and b[0].
//
// Layer unitary = CP * D * S * P * HH * CNOT (CP,S,P diagonal, HH*CNOT a
// constant +-0.5 real matrix). EVERY wave redundantly computes, per lane
// t=4*i+j (lanes>=16 duplicate): L[i][j] = sum_k D4[i][k]*hh_k*e^{i th_k}
// closed-form per-lane, then U = L@U via shuffle matmul per extra layer,
// M = U^dag Z U, A = Re(Dp^dag M Dp). The 10 needed A-elements are gathered
// by __shfl; each thread folds W,b into 9 private coefficients.
// Prelude latency hides under the 4 hoisted streaming loads; no cross-wave
// communication at all.
//
// Streaming: thread handles 8 samples = 4 lane-contiguous float4 loads
// (1 KB/wave/instr) and 4 float2 stores. Grid sized so one pass covers B.
// ============================================================================

__device__ inline float2 eval_f4(float4 X,
                                 float k00, float k01, float k02,
                                 float k10, float k11, float k12,
                                 float k20, float k21, float k22) {
    float s0, c0, s1, c1;
    float2 r;
    __sincosf(X.x, &s0, &c0);
    __sincosf(X.y, &s1, &c1);
    r.x = fmaf(s0, fmaf(s1, k22, fmaf(c1, k21, k20)),
          fmaf(c0, fmaf(s1, k12, fmaf(c1, k11, k10)),
                   fmaf(s1, k02, fmaf(c1, k01, k00))));
    __sincosf(X.z, &s0, &c0);
    __sincosf(X.w, &s1, &c1);
    r.y = fmaf(s0, fmaf(s1, k22, fmaf(c1, k21, k20)),
          fmaf(c0, fmaf(s1, k12, fmaf(c1, k11, k10)),
                   fmaf(s1, k02, fmaf(c1, k01, k00))));
    return r;
}

__global__ __launch_bounds__(256) void fraud_fused(
        const float* __restrict__ params, int n_layers,
        const float* __restrict__ W, const float* __restrict__ bias,
        const float4* __restrict__ x4, float2* __restrict__ out2, int n4) {
    const int t = threadIdx.x;
    const int lane = t & 63;
    const int gw = (blockIdx.x * 256 + t) >> 6;   // global wave id
    const int f4b = gw * 256 + lane;              // this lane's first float4

    // -------- issue all streaming loads FIRST (HBM busy during prelude) -----
    float4 X0, X1, X2, X3;
    const bool b0 = f4b < n4, b1 = f4b + 64 < n4,
               b2 = f4b + 128 < n4, b3 = f4b + 192 < n4;
    if (b0) X0 = x4[f4b];
    if (b1) X1 = x4[f4b + 64];
    if (b2) X2 = x4[f4b + 128];
    if (b3) X3 = x4[f4b + 192];
    const float w = W[0], bb = bias[0];

    // -------- per-wave prelude (redundant across waves, no barriers) --------
    const int i = (lane >> 2) & 3, j = lane & 3;
    const int i0 = i >> 1, i1 = i & 1;

    float Ur = (i == j) ? 1.f : 0.f, Ui = 0.f;

    for (int l = 0; l < n_layers; ++l) {
        float p[14];
        #pragma unroll
        for (int q = 0; q < 14; ++q) {
            float vv = params[l * 14 + q];
            float lim = (q < 12) ? 5.0f : 1.0f;
            p[q] = fminf(fmaxf(vv, -lim), lim);
        }
        float t0 = p[4] + p[6], t1 = p[5] + p[7];

        // D rows this lane needs (closed form, independent sincos)
        float sn8,  cs8;  __sincosf(0.5f * p[8],  &sn8,  &cs8);
        float sd10, cd10; __sincosf(0.5f * p[10], &sd10, &cd10);
        float sn9,  cs9;  __sincosf(0.5f * p[9],  &sn9,  &cs9);
        float sd11, cd11; __sincosf(0.5f * p[11], &sd11, &cd11);
        float mag00 = (i0 == 0) ?  cd10 : sd10;
        float mag01 = (i0 == 0) ? -sd10 : cd10;
        float d00r = mag00 * cs8, d00i = -mag00 * sn8;
        float d01r = mag01 * cs8, d01i =  mag01 * sn8;
        float mag10 = (i1 == 0) ?  cd11 : sd11;
        float mag11 = (i1 == 0) ? -sd11 : cd11;
        float e10r = mag10 * cs9, e10i = -mag10 * sn9;
        float e11r = mag11 * cs9, e11i =  mag11 * sn9;

        // L[i][j] = sum_k D4[i][k] * hh_k * e^{i th_k}   (all per-lane)
        int sj = j ^ (j >> 1);               // HHC col swap 2<->3
        float Lr = 0.f, Li = 0.f;
        #pragma unroll
        for (int k = 0; k < 4; ++k) {
            int k0 = k >> 1, k1 = k & 1;
            float ar = k0 ? d01r : d00r, ai = k0 ? d01i : d00i;
            float br = k1 ? e11r : e10r, bi = k1 ? e11i : e10i;
            float Dr = ar * br - ai * bi;
            float Di = ar * bi + ai * br;
            float th = p[2] * (float)k0 + p[3] * (float)k1
                     + 0.5f * t0 * (float)(2 * k0 - 1)
                     + 0.5f * t1 * (float)(2 * k1 - 1);
            float sth, cth; __sincosf(th, &sth, &cth);
            float hh = (__popc(k & sj) & 1) ? -0.5f : 0.5f;
            float Er2 = hh * cth, Ei2 = hh * sth;
            Lr += Dr * Er2 - Di * Ei2;
            Li += Dr * Ei2 + Di * Er2;
        }
        if (i == 3) {                        // CP: row-3 phase
            float cps, cpc; __sincosf(p[12] + p[13], &cps, &cpc);
            float nr = Lr * cpc - Li * cps;
            float ni = Lr * cps + Li * cpc;
            Lr = nr; Li = ni;
        }

        if (l == 0) { Ur = Lr; Ui = Li; }
        else {
            float nr = 0.f, ni = 0.f;
            #pragma unroll
            for (int k = 0; k < 4; ++k) {
                float ar = __shfl(Lr, 4 * i + k, 64);
                float ai = __shfl(Li, 4 * i + k, 64);
                float br = __shfl(Ur, 4 * k + j, 64);
                float bi = __shfl(Ui, 4 * k + j, 64);
                nr = fmaf(ar, br, fmaf(-ai, bi, nr));
                ni = fmaf(ar, bi, fmaf(ai, br, ni));
            }
            Ur = nr; Ui = ni;
        }
    }

    // M[i][j] = sum_k z_k conj(U[k][i]) U[k][j];  A = Re(conj(dph_i) M dph_j)
    float mr = 0.f, mi = 0.f;
    #pragma unroll
    for (int k = 0; k < 4; ++k) {
        float z = (k < 2) ? 1.f : -1.f;
        float u1r =  __shfl(Ur, 4 * k + i, 64);
        float u1i = -__shfl(Ui, 4 * k + i, 64);
        float u2r =  __shfl(Ur, 4 * k + j, 64);
        float u2i =  __shfl(Ui, 4 * k + j, 64);
        mr += z * (u1r * u2r - u1i * u2i);
        mi += z * (u1r * u2i + u1i * u2r);
    }
    float dri = (i == 0) ? 1.f : ((i == 3) ? -1.f : 0.f);
    float dii = (i == 0 || i == 3) ? 0.f : -1.f;
    float drj = (j == 0) ? 1.f : ((j == 3) ? -1.f : 0.f);
    float dij = (j == 0 || j == 3) ? 0.f : -1.f;
    float fr = dri * drj + dii * dij;
    float fi = dri * dij - dii * drj;
    float Aval = mr * fr - mi * fi;          // lanes 0..15 hold A[i][j]

    // gather the 10 distinct A elements (A symmetric in the used combos)
    float A00 = __shfl(Aval, 0, 64),  A01 = __shfl(Aval, 1, 64);
    float A02 = __shfl(Aval, 2, 64),  A03 = __shfl(Aval, 3, 64);
    float A11 = __shfl(Aval, 5, 64),  A12 = __shfl(Aval, 6, 64);
    float A13 = __shfl(Aval, 7, 64),  A22 = __shfl(Aval, 10, 64);
    float A23 = __shfl(Aval, 11, 64), A33 = __shfl(Aval, 15, 64);

    float k00 = 0.25f * (A00 + A11 + A22 + A33) * w + bb;
    float k01 = 0.25f * (A00 - A11 + A22 - A33) * w;
    float k02 = 0.5f  * (A01 + A23) * w;
    float k10 = 0.25f * (A00 + A11 - A22 - A33) * w;
    float k11 = 0.25f * (A00 - A11 - A22 + A33) * w;
    float k12 = 0.5f  * (A01 - A23) * w;
    float k20 = 0.5f  * (A02 + A13) * w;
    float k21 = 0.5f  * (A02 - A13) * w;
    float k22 = 0.5f  * (A03 + A12) * w;

    // -------- consume hoisted loads, store ----------------------------------
    if (b0) out2[f4b]       = eval_f4(X0, k00,k01,k02,k10,k11,k12,k20,k21,k22);
    if (b1) out2[f4b + 64]  = eval_f4(X1, k00,k01,k02,k10,k11,k12,k20,k21,k22);
    if (b2) out2[f4b + 128] = eval_f4(X2, k00,k01,k02,k10,k11,k12,k20,k21,k22);
    if (b3) out2[f4b + 192] = eval_f4(X3, k00,k01,k02,k10,k11,k12,k20,k21,k22);
}

extern "C" void kernel_launch(void* const* d_in, const int* in_sizes, int n_in,
                              void* d_out, int out_size, void* d_ws, size_t ws_size,
                              hipStream_t stream) {
    const float* x      = (const float*)d_in[0];
    const float* params = (const float*)d_in[1];
    const float* W      = (const float*)d_in[2];
    const float* b      = (const float*)d_in[3];
    float* out = (float*)d_out;

    int n_layers = in_sizes[1] / 14;
    int B = out_size;                 // n_classes == 1
    int n4 = B / 2;                   // float4 elements in x (B*2 floats / 4)

    // each thread consumes 4 float4s => 1024 float4s per block
    int blocks = (n4 + 1023) / 1024;  // B=4194304 -> 2048 blocks, one pass

    fraud_fused<<<blocks, 256, 0, stream>>>(params, n_layers, W, b,
                                            (const float4*)x, (float2*)out, n4);
}

// Round 7
// 12.926 us; speedup vs baseline: 1.4745x; 1.4745x over previous
//
#include <hip/hip_runtime.h>
#include <math.h>

// ============================================================================
// Single fused kernel (round-4 structure + nontemporal float4 stores).
//
// logit(x0,x1) = u0^T K u1,  u0=[1,cos x0,sin x0], u1=[1,cos x1,sin x1],
// K folded with W[0] and b[0].
//
// Layer unitary = CP * D * S * P * HH * CNOT. CP,S,P diagonal; HH*CNOT is a
// constant real +-0.5 matrix (HH cols 2,3 swapped). Wave 0 computes the 4x4
// A-matrix (lane t=4*i+j owns element (i,j); per-lane closed-form L, shuffle
// matmuls for U-chaining and M), publishes 16 floats via LDS; one barrier;
// every thread folds W,b into 9 private coefficients and streams.
//
// Streaming: 2 quad-iterations/thread, float4 loads + float4 NT stores
// (out is write-only; NT keeps L2 for the x stream across graph replays).
// ============================================================================

typedef float f32x4 __attribute__((ext_vector_type(4)));

__device__ inline float eval_sample(float x0, float x1,
                                    float k00, float k01, float k02,
                                    float k10, float k11, float k12,
                                    float k20, float k21, float k22) {
    float s0, c0, s1, c1;
    __sincosf(x0, &s0, &c0);
    __sincosf(x1, &s1, &c1);
    float e0 = fmaf(s1, k02, fmaf(c1, k01, k00));
    float e1 = fmaf(s1, k12, fmaf(c1, k11, k10));
    float e2 = fmaf(s1, k22, fmaf(c1, k21, k20));
    return fmaf(s0, e2, fmaf(c0, e1, e0));
}

__global__ __launch_bounds__(256) void fraud_fused(
        const float* __restrict__ params, int n_layers,
        const float* __restrict__ W, const float* __restrict__ bias,
        const float4* __restrict__ x, f32x4* __restrict__ out, int nquads) {
    __shared__ float Am[16];

    const int t = threadIdx.x;
    const int gsize = gridDim.x * 256;
    const int q0 = blockIdx.x * 256 + t;
    const int q1 = q0 + gsize;
    const bool v0 = q0 < nquads, v1 = q1 < nquads;

    // -------- issue streaming loads FIRST: HBM busy during the prelude ------
    float4 xa0, xb0, xa1, xb1;
    if (v0) { xa0 = x[2 * q0]; xb0 = x[2 * q0 + 1]; }
    if (v1) { xa1 = x[2 * q1]; xb1 = x[2 * q1 + 1]; }
    const float w = W[0], bb = bias[0];

    // -------- wave 0: prelude ----------------------------------------------
    if (t < 64) {  // lanes >=16 compute harmless duplicates
        const int i = (t >> 2) & 3, j = t & 3;
        const int i0 = i >> 1, i1 = i & 1;

        float Ur = (i == j) ? 1.f : 0.f, Ui = 0.f;

        for (int l = 0; l < n_layers; ++l) {
            float p[14];
            #pragma unroll
            for (int q = 0; q < 14; ++q) {
                float vv = params[l * 14 + q];
                float lim = (q < 12) ? 5.0f : 1.0f;
                p[q] = fminf(fmaxf(vv, -lim), lim);
            }
            float t0 = p[4] + p[6], t1 = p[5] + p[7];

            // D rows needed by this lane (closed form, independent sincos)
            float sn8,  cs8;  __sincosf(0.5f * p[8],  &sn8,  &cs8);
            float sd10, cd10; __sincosf(0.5f * p[10], &sd10, &cd10);
            float sn9,  cs9;  __sincosf(0.5f * p[9],  &sn9,  &cs9);
            float sd11, cd11; __sincosf(0.5f * p[11], &sd11, &cd11);
            float mag00 = (i0 == 0) ?  cd10 : sd10;
            float mag01 = (i0 == 0) ? -sd10 : cd10;
            float d00r = mag00 * cs8, d00i = -mag00 * sn8;
            float d01r = mag01 * cs8, d01i =  mag01 * sn8;
            float mag10 = (i1 == 0) ?  cd11 : sd11;
            float mag11 = (i1 == 0) ? -sd11 : cd11;
            float e10r = mag10 * cs9, e10i = -mag10 * sn9;
            float e11r = mag11 * cs9, e11i =  mag11 * sn9;

            // L[i][j] = sum_k D4[i][k] * hh_k * e^{i th_k}   (all per-lane)
            int sj = j ^ (j >> 1);           // HHC col swap 2<->3
            float Lr = 0.f, Li = 0.f;
            #pragma unroll
            for (int k = 0; k < 4; ++k) {
                int k0 = k >> 1, k1 = k & 1;
                float ar = k0 ? d01r : d00r, ai = k0 ? d01i : d00i;
                float br = k1 ? e11r : e10r, bi = k1 ? e11i : e10i;
                float Dr = ar * br - ai * bi;
                float Di = ar * bi + ai * br;
                float th = p[2] * (float)k0 + p[3] * (float)k1
                         + 0.5f * t0 * (float)(2 * k0 - 1)
                         + 0.5f * t1 * (float)(2 * k1 - 1);
                float sth, cth; __sincosf(th, &sth, &cth);
                float hh = (__popc(k & sj) & 1) ? -0.5f : 0.5f;
                float Er2 = hh * cth, Ei2 = hh * sth;
                Lr += Dr * Er2 - Di * Ei2;
                Li += Dr * Ei2 + Di * Er2;
            }
            if (i == 3) {                    // CP: row-3 phase
                float cps, cpc; __sincosf(p[12] + p[13], &cps, &cpc);
                float nr = Lr * cpc - Li * cps;
                float ni = Lr * cps + Li * cpc;
                Lr = nr; Li = ni;
            }

            // U = L @ U (layer 0: U == I, copy)
            if (l == 0) { Ur = Lr; Ui = Li; }
            else {
                float nr = 0.f, ni = 0.f;
                #pragma unroll
                for (int k = 0; k < 4; ++k) {
                    float ar = __shfl(Lr, 4 * i + k, 64);
                    float ai = __shfl(Li, 4 * i + k, 64);
                    float br = __shfl(Ur, 4 * k + j, 64);
                    float bi = __shfl(Ui, 4 * k + j, 64);
                    nr = fmaf(ar, br, fmaf(-ai, bi, nr));
                    ni = fmaf(ar, bi, fmaf(ai, br, ni));
                }
                Ur = nr; Ui = ni;
            }
        }

        // M[i][j] = sum_k z_k conj(U[k][i]) U[k][j]
        float mr = 0.f, mi = 0.f;
        #pragma unroll
        for (int k = 0; k < 4; ++k) {
            float z = (k < 2) ? 1.f : -1.f;
            float u1r =  __shfl(Ur, 4 * k + i, 64);
            float u1i = -__shfl(Ui, 4 * k + i, 64);
            float u2r =  __shfl(Ur, 4 * k + j, 64);
            float u2i =  __shfl(Ui, 4 * k + j, 64);
            mr += z * (u1r * u2r - u1i * u2i);
            mi += z * (u1r * u2i + u1i * u2r);
        }
        // A = Re(conj(dph_i) * M * dph_j), dph = (1, -i, -i, -1)
        float dri = (i == 0) ? 1.f : ((i == 3) ? -1.f : 0.f);
        float dii = (i == 0 || i == 3) ? 0.f : -1.f;
        float drj = (j == 0) ? 1.f : ((j == 3) ? -1.f : 0.f);
        float dij = (j == 0 || j == 3) ? 0.f : -1.f;
        float fr = dri * drj + dii * dij;
        float fi = dri * dij - dii * drj;
        if (t < 16) Am[t] = mr * fr - mi * fi;
    }
    __syncthreads();

    // -------- fold coefficients (per thread, registers) ---------------------
    float A00 = Am[0],  A01 = Am[1],  A02 = Am[2],  A03 = Am[3];
    float A11 = Am[5],  A12 = Am[6],  A13 = Am[7];
    float A22 = Am[10], A23 = Am[11], A33 = Am[15];
    float k00 = 0.25f * (A00 + A11 + A22 + A33) * w + bb;
    float k01 = 0.25f * (A00 - A11 + A22 - A33) * w;
    float k02 = 0.5f  * (A01 + A23) * w;
    float k10 = 0.25f * (A00 + A11 - A22 - A33) * w;
    float k11 = 0.25f * (A00 - A11 - A22 + A33) * w;
    float k12 = 0.5f  * (A01 - A23) * w;
    float k20 = 0.5f  * (A02 + A13) * w;
    float k21 = 0.5f  * (A02 - A13) * w;
    float k22 = 0.5f  * (A03 + A12) * w;

    // -------- consume hoisted loads, NT store -------------------------------
    if (v0) {
        f32x4 o;
        o.x = eval_sample(xa0.x, xa0.y, k00, k01, k02, k10, k11, k12, k20, k21, k22);
        o.y = eval_sample(xa0.z, xa0.w, k00, k01, k02, k10, k11, k12, k20, k21, k22);
        o.z = eval_sample(xb0.x, xb0.y, k00, k01, k02, k10, k11, k12, k20, k21, k22);
        o.w = eval_sample(xb0.z, xb0.w, k00, k01, k02, k10, k11, k12, k20, k21, k22);
        __builtin_nontemporal_store(o, &out[q0]);
    }
    if (v1) {
        f32x4 o;
        o.x = eval_sample(xa1.x, xa1.y, k00, k01, k02, k10, k11, k12, k20, k21, k22);
        o.y = eval_sample(xa1.z, xa1.w, k00, k01, k02, k10, k11, k12, k20, k21, k22);
        o.z = eval_sample(xb1.x, xb1.y, k00, k01, k02, k10, k11, k12, k20, k21, k22);
        o.w = eval_sample(xb1.z, xb1.w, k00, k01, k02, k10, k11, k12, k20, k21, k22);
        __builtin_nontemporal_store(o, &out[q1]);
    }
    // generic tail (not taken for B = 4194304 with 2048 blocks)
    for (int q = q1 + gsize; q < nquads; q += gsize) {
        float4 xa = x[2 * q];
        float4 xb = x[2 * q + 1];
        f32x4 o;
        o.x = eval_sample(xa.x, xa.y, k00, k01, k02, k10, k11, k12, k20, k21, k22);
        o.y = eval_sample(xa.z, xa.w, k00, k01, k02, k10, k11, k12, k20, k21, k22);
        o.z = eval_sample(xb.x, xb.y, k00, k01, k02, k10, k11, k12, k20, k21, k22);
        o.w = eval_sample(xb.z, xb.w, k00, k01, k02, k10, k11, k12, k20, k21, k22);
        __builtin_nontemporal_store(o, &out[q]);
    }
}

extern "C" void kernel_launch(void* const* d_in, const int* in_sizes, int n_in,
                              void* d_out, int out_size, void* d_ws, size_t ws_size,
                              hipStream_t stream) {
    const float* x      = (const float*)d_in[0];
    const float* params = (const float*)d_in[1];
    const float* W      = (const float*)d_in[2];
    const float* b      = (const float*)d_in[3];
    float* out = (float*)d_out;

    int n_layers = in_sizes[1] / 14;
    int B = out_size;              // n_classes == 1
    int nq = B / 4;                // B = 4194304, divisible by 4

    int blocks = (nq + 511) / 512; // 2 quad-iterations per thread
    if (blocks > 2048) blocks = 2048;  // 8 blocks/CU, one resident pass

    fraud_fused<<<blocks, 256, 0, stream>>>(params, n_layers, W, b,
                                            (const float4*)x, (f32x4*)out, nq);
}